// Round 9
// baseline (137.862 us; speedup 1.0000x reference)
//
#include <hip/hip_runtime.h>
#include <hip/hip_bf16.h>
#include <math.h>

#define S_LEN 2048
#define BSZ 2
#define DM 512
#define NH 8
#define HD 64
#define RTOT (S_LEN*BSZ)             // 4096 rows, row r = s*BSZ + b
#define T_KEEP 32
#define ROW0 ((S_LEN - T_KEEP)*BSZ)  // 4032
#define NXELEM (RTOT*DM)             // 2097152
#define NWROW  (NH*192)              // 1536
#define NWELEM (NWROW*DM)            // 786432

typedef __attribute__((ext_vector_type(8))) _Float16 half8;
typedef __attribute__((ext_vector_type(4))) float floatx4;

__device__ __forceinline__ void gld16(const void* g, void* l) {
    __builtin_amdgcn_global_load_lds((const __attribute__((address_space(1))) void*)g,
                                     (__attribute__((address_space(3))) void*)l, 16, 0, 0);
}

__device__ __forceinline__ short cvt1(float v) {
    _Float16 h = (_Float16)v;
    return __builtin_bit_cast(short, h);
}

// ---- Kernel 0: fp32 -> fp16 planes + bias concat + WoT transpose + fills ------
__global__ __launch_bounds__(256) void convert(
    const float* __restrict__ x,
    const float* __restrict__ Wq, const float* __restrict__ Wk, const float* __restrict__ Wv,
    const float* __restrict__ bq, const float* __restrict__ bk, const float* __restrict__ bv,
    const float* __restrict__ Wo, const float* __restrict__ bo,
    short* __restrict__ xf, short* __restrict__ wf, float* __restrict__ bcat,
    float* __restrict__ WoT, float* __restrict__ gbar, float* __restrict__ out)
{
    const int g = blockIdx.x*blockDim.x + threadIdx.x;
    const int stride = gridDim.x*blockDim.x;
    const int total4 = (NXELEM + NWELEM)/4;
    for (int i = g; i < total4; i += stride) {
        float4 v; size_t dst; short* d;
        if (i < NXELEM/4) {
            v = ((const float4*)x)[i];
            dst = (size_t)i*4; d = xf;
        } else {
            int j = i - NXELEM/4;
            int e = j*4;
            int R = e >> 9;
            int k = e & 511;
            int t = R >> 6;                 // = h*3 + m
            int hh = (t*683) >> 11;         // t/3 for t<24
            int m = t - 3*hh;
            int c = R & 63;
            const float* W = (m == 0 ? Wq : (m == 1 ? Wk : Wv));
            v = *(const float4*)&W[(size_t)(hh*HD + c)*DM + k];
            dst = (size_t)R*DM + k; d = wf;
        }
        short4 hv;
        hv.x = cvt1(v.x); hv.y = cvt1(v.y); hv.z = cvt1(v.z); hv.w = cvt1(v.w);
        *(short4*)&d[dst] = hv;
    }
    // Wo transpose (coalesced reads, scattered 4B writes)
    for (int i = g; i < DM*DM/4; i += stride) {
        int c  = i >> 7;           // 0..511
        int k4 = (i & 127)*4;
        float4 v = *(const float4*)&Wo[(size_t)c*DM + k4];
        WoT[(size_t)(k4+0)*DM + c] = v.x;
        WoT[(size_t)(k4+1)*DM + c] = v.y;
        WoT[(size_t)(k4+2)*DM + c] = v.z;
        WoT[(size_t)(k4+3)*DM + c] = v.w;
    }
    // background fill: rows < ROW0 of out are just bo
    {
        const float4* b4 = (const float4*)bo;
        float4* o4 = (float4*)out;
        const int fill4 = ROW0*DM/4;
        for (int i = g; i < fill4; i += stride) o4[i] = b4[i & 127];
    }
    if (g < NWROW) {
        int t = g >> 6;
        int hh = (t*683) >> 11;
        int m = t - 3*hh;
        int c = g & 63;
        bcat[g] = (m == 0 ? bq : (m == 1 ? bk : bv))[hh*HD + c];
    }
    if (g < 2048) gbar[g] = 0.f;
}

// ------------- Kernel 1: fp16 MFMA qkv GEMM, LDS-staged, 4 blocks/CU -----------
// grid (128, 8): block = 32 rows x head h's 192 cols. BK=64, 8 K-iterations.
// Waves 2x2: wave (rowg,colg) computes 16 rows x 96 cols (6 MFMA per kh).
// LDS stage 28KB in 1KB frag chunks: A[4] then B[24]; C-dump (24KB) reuses it.
__global__ __launch_bounds__(256, 4) void qkv_gemm(
    const _Float16* __restrict__ xf, const _Float16* __restrict__ wf,
    const float* __restrict__ bcat, const float* __restrict__ beta,
    float* __restrict__ gbar, float* __restrict__ qsel)
{
    __shared__ __align__(16) char smem[28672];
    __shared__ float sb[256];

    const int tid  = threadIdx.x;
    const int w    = tid >> 6;
    const int lane = tid & 63;
    const int lrow = lane & 15;
    const int lk8  = lane >> 4;
    const int h    = blockIdx.y;
    const int r0   = blockIdx.x * 32;
    const int rowg = w >> 1;
    const int colg = w & 1;

    floatx4 acc[6];
    #pragma unroll
    for (int j = 0; j < 6; ++j) acc[j] = (floatx4)0.f;

    // staging sources: wave w stages A chunk w (f=w>>1, kh=w&1) and B chunks 6w..6w+5
    const _Float16* asrc = xf + (size_t)(r0 + (w>>1)*16 + lrow)*DM + (w&1)*32 + lk8*8;
    const _Float16* bsrc[6];
    #pragma unroll
    for (int ii = 0; ii < 6; ++ii)
        bsrc[ii] = wf + (size_t)(h*192 + (3*w + (ii>>1))*16 + lrow)*DM + (ii&1)*32 + lk8*8;

    for (int kc = 0; kc < 8; ++kc) {
        const int ko = kc*64;
        gld16(asrc + ko, smem + w*1024);
        #pragma unroll
        for (int ii = 0; ii < 6; ++ii)
            gld16(bsrc[ii] + ko, smem + 4096 + (6*w + ii)*1024);
        __syncthreads();
        #pragma unroll
        for (int kh = 0; kh < 2; ++kh) {
            half8 a = *(const half8*)(smem + (rowg*2 + kh)*1024 + lane*16);
            #pragma unroll
            for (int j = 0; j < 6; ++j) {
                half8 b = *(const half8*)(smem + 4096 + ((colg*6 + j)*2 + kh)*1024 + lane*16);
                acc[j] = __builtin_amdgcn_mfma_f32_16x16x32_f16(a, b, acc[j], 0, 0, 0);
            }
        }
        __syncthreads();
    }

    // C dump (32 x 192 fp32 = 24KB, reuses stage)
    float* Cl = (float*)smem;
    #pragma unroll
    for (int j = 0; j < 6; ++j) {
        int col = colg*96 + j*16 + lrow;
        float bias = bcat[h*192 + col];
        #pragma unroll
        for (int reg = 0; reg < 4; ++reg) {
            int row = rowg*16 + lk8*4 + reg;
            Cl[row*192 + col] = acc[j][reg] + bias;
        }
    }
    sb[tid] = 0.f;
    __syncthreads();

    const float inv_scale = 1.0f / (8.0f * expf(beta[h]));
    float kacc0 = 0.f, kacc1 = 0.f, vacc0 = 0.f, vacc1 = 0.f;
    for (int i2 = w; i2 < 32; i2 += 4) {
        float qv = Cl[i2*192 + lane];
        float kv = Cl[i2*192 + 64 + lane];
        float vv = Cl[i2*192 + 128 + lane];
        int r = r0 + i2;
        int s = r >> 1;
        int b = r & 1;
        if ((s & 63) == 63) {
            int wi = s >> 6;
            qsel[((size_t)(b*NH + h)*T_KEEP + wi)*64 + lane] = qv;
        }
        float p = qv * kv;
        #pragma unroll
        for (int off = 32; off > 0; off >>= 1) p += __shfl_xor(p, off, 64);
        float sig = 1.0f / (1.0f + expf(-p * inv_scale));
        if (b == 0) { kacc0 += sig*kv; vacc0 += sig*vv; }
        else        { kacc1 += sig*kv; vacc1 += sig*vv; }
    }
    __syncthreads();

    atomicAdd(&sb[  0 + lane], kacc0);
    atomicAdd(&sb[ 64 + lane], vacc0);
    atomicAdd(&sb[128 + lane], kacc1);
    atomicAdd(&sb[192 + lane], vacc1);
    __syncthreads();
    {
        int b   = tid >> 7;
        int sel = (tid >> 6) & 1;
        int j   = tid & 63;
        int z   = b*NH + h;
        atomicAdd(&gbar[sel*1024 + z*64 + j], sb[tid]);
    }
}

// ------------- Kernel 2: fused coef softmax + u-vector + WoT matvec ------------
// grid 64: block a -> output row ROW0+a (a = wi*2 + b).
// out[a] = bo + WoT^T-matvec(u),  u[h*64+j] = coef[b,h]*vbar[b,h,j]
__global__ __launch_bounds__(256) void outk4(
    const float* __restrict__ qsel, const float* __restrict__ beta,
    const float* __restrict__ gbar, const float* __restrict__ WoT,
    const float* __restrict__ bo, float* __restrict__ out)
{
    const int a = blockIdx.x;
    const int b = a & 1;
    const int wi_blk = a >> 1;
    const int tid = threadIdx.x;

    __shared__ float s_kb[512];
    __shared__ float s_u[512];     // first coef slots s_cf, then u
    __shared__ float s_cf[NH];
    __shared__ float s_part[512];

    s_kb[tid]       = gbar[b*512 + tid];
    s_kb[tid] = gbar[b*512 + tid];                 // kbar for z=b*8..b*8+7
    s_part[tid]     = gbar[1024 + b*512 + tid];    // vbar (temp home)
    s_part[tid+256] = gbar[1024 + b*512 + 256 + tid];
    if (tid < 256) s_kb[tid+256] = gbar[b*512 + 256 + tid];
    __syncthreads();

    // scores + softmax: thread (h = tid>>5, wi = tid&31), 32-lane groups
    {
        int h = tid >> 5, wi = tid & 31;
        const float* qrow = &qsel[((size_t)(b*NH + h)*T_KEEP + wi)*64];
        float sc = 0.f;
        #pragma unroll
        for (int j = 0; j < 64; j += 4) {
            float4 q = *(const float4*)&qrow[j];
            sc += q.x*s_kb[h*64+j] + q.y*s_kb[h*64+j+1] + q.z*s_kb[h*64+j+2] + q.w*s_kb[h*64+j+3];
        }
        sc *= 1.0f / (8.0f * expf(beta[h]));
        float m = sc;
        #pragma unroll
        for (int off = 16; off > 0; off >>= 1) m = fmaxf(m, __shfl_xor(m, off, 32));
        m = fmaxf(m, 0.f);                      // sink logit = 0
        float e = expf(sc - m);
        float d = e;
        #pragma unroll
        for (int off = 16; off > 0; off >>= 1) d += __shfl_xor(d, off, 32);
        d += expf(-m);                          // sink term
        if (wi == wi_blk) {
            float c = e / d;
            if (wi_blk == T_KEEP-1) c += 1.0f;  // iter-0 contribution
            s_cf[h] = c;
        }
    }
    __syncthreads();
    // u[k] = coef[h] * vbar[h][j]
    s_u[tid]       = s_cf[tid >> 6]         * s_part[tid];
    s_u[tid + 256] = s_cf[(tid + 256) >> 6] * s_part[tid + 256];
    __syncthreads();

    // matvec: thread (c0 = (tid&127)*4, khalf = tid>>7), 256 k each
    const int c0 = (tid & 127)*4;
    const int kh = tid >> 7;
    float4 accv = {0.f, 0.f, 0.f, 0.f};
    for (int k = kh*256; k < kh*256 + 256; ++k) {
        float u = s_u[k];
        float4 wv = *(const float4*)&WoT[(size_t)k*DM + c0];
        accv.x += u*wv.x; accv.y += u*wv.y; accv.z += u*wv.z; accv.w += u*wv.w;
    }
    __syncthreads();
    if (kh == 1) *(float4*)&s_part[c0] = accv;
    __syncthreads();
    if (kh == 0) {
        float4 pv = *(const float4*)&s_part[c0];
        float4 bv = *(const float4*)&bo[c0];
        accv.x += pv.x + bv.x; accv.y += pv.y + bv.y;
        accv.z += pv.z + bv.z; accv.w += pv.w + bv.w;
        *(float4*)&out[(size_t)(ROW0 + a)*DM + c0] = accv;
    }
}

extern "C" void kernel_launch(void* const* d_in, const int* in_sizes, int n_in,
                              void* d_out, int out_size, void* d_ws, size_t ws_size,
                              hipStream_t stream) {
    const float* x    = (const float*)d_in[0];
    const float* Wq   = (const float*)d_in[1];
    const float* bq   = (const float*)d_in[2];
    const float* Wk   = (const float*)d_in[3];
    const float* bk   = (const float*)d_in[4];
    const float* Wv   = (const float*)d_in[5];
    const float* bv   = (const float*)d_in[6];
    const float* Wo   = (const float*)d_in[7];
    const float* bo   = (const float*)d_in[8];
    const float* beta = (const float*)d_in[9];

    char* ws = (char*)d_ws;
    float* gbar = (float*)(ws + 0);           //   8 KB
    float* qsel = (float*)(ws + 8192);        // 128 KB
    float* bcat = (float*)(ws + 139264);      //   8 KB
    float* WoT  = (float*)(ws + 147456);      //   1 MB
    short* xf   = (short*)(ws + 1196032);     //   4 MB
    short* wf   = (short*)(ws + 1196032 + 4194304);   // 1.5 MB
    float* out  = (float*)d_out;

    convert<<<1024, 256, 0, stream>>>(x, Wq, Wk, Wv, bq, bk, bv, Wo, bo,
                                      xf, wf, bcat, WoT, gbar, out);
    dim3 g1(RTOT/32, NH);
    qkv_gemm<<<g1, 256, 0, stream>>>((const _Float16*)xf, (const _Float16*)wf,
                                     bcat, beta, gbar, qsel);
    outk4<<<64, 256, 0, stream>>>(qsel, beta, gbar, WoT, bo, out);
}